// Round 13
// baseline (468.069 us; speedup 1.0000x reference)
//
#include <hip/hip_runtime.h>

#define CIN    256
#define WID    48
#define HWD    2304            // 48*48
#define PHW    2500            // 50*50 padded
#define NTB    64              // ts(16) * b(4)
#define SLICE  (4*CIN*HWD)

// workspace (bytes); ws >= 150,994,944 known-safe
#define WS_XT  0               // Xtp half: 32*4*2500*64*2 = 40,960,000
#define WS_AT  40960000        // A-tiles : 2*36*8192*2   =  1,179,648
#define WS_Y   42139648        // Y bf16  : 64*256*2304*2 = 75,497,472 (ends 117,637,120)

typedef __attribute__((ext_vector_type(8))) short short8v;  // 8 bf16
typedef __attribute__((ext_vector_type(4))) float f32x4;

__device__ __forceinline__ unsigned short f2bf(float f) {
    unsigned u = __float_as_uint(f);
    u = (u + 0x7fffu + ((u >> 16) & 1u)) >> 16;   // RNE
    return (unsigned short)u;
}
__device__ __forceinline__ float bf2f(unsigned short s) {
    return __uint_as_float(((unsigned)s) << 16);
}
__device__ __forceinline__ void gload_lds16(const void* g, void* l) {
    __builtin_amdgcn_global_load_lds(
        (const __attribute__((address_space(1))) unsigned int*)g,
        (__attribute__((address_space(3))) unsigned int*)l, 16, 0, 0);
}

// ---- prep_w: W fp32 -> At bf16, pre-swizzled LDS image, tile order kt2 = g*9 + tap
__global__ __launch_bounds__(256) void prep_w_k(const float* __restrict__ Wt,
                                                unsigned short* __restrict__ At)
{
    const int s = (blockIdx.x * 256 + threadIdx.x) * 8;   // short index < 589824
    const int tile = s >> 13;                 // by*36 + kt2
    const int row  = (s & 8191) >> 6;
    const int colb = (s & 63) * 2;            // byte col (16B-aligned)
    const int by = tile / 36, kt2 = tile - by * 36;
    const int g = kt2 / 9, tap = kt2 - g * 9;
    const int k0 = (colb ^ ((row & 7) << 4)) >> 1;   // elem 0..63, 8-aligned
    const int co = by * 128 + row;
    const float* wp = Wt + (size_t)co * 2304 + (g * 64 + k0) * 9 + tap;
    short8v v;
    #pragma unroll
    for (int j = 0; j < 8; ++j) v[j] = (short)f2bf(wp[j * 9]);
    *(short8v*)(At + s) = v;
}

// ---- prep_x: X fp32 [32tb][ci][px] -> Xtp bf16 [32tb][g][pp(2500)][64ci], halo stays zero
__global__ __launch_bounds__(256) void prep_x_k(const float* __restrict__ X,
                                                unsigned short* __restrict__ Xtp)
{
    __shared__ unsigned short t_[64][72];
    const int tid = threadIdx.x;
    const int px0 = blockIdx.x * 64;
    const int g   = blockIdx.y;               // ci group of 64
    const int tb  = blockIdx.z;

    const int ci_l = tid >> 2, pg = (tid & 3) * 16;
    const float* xp = X + ((size_t)tb * CIN + g * 64 + ci_l) * HWD + px0 + pg;
    #pragma unroll
    for (int q = 0; q < 4; ++q) {
        f32x4 v = *(const f32x4*)(xp + q * 4);
        #pragma unroll
        for (int e = 0; e < 4; ++e)
            t_[pg + q * 4 + e][ci_l] = f2bf(v[e]);
    }
    __syncthreads();
    const int px_l = tid >> 2, cg = (tid & 3) * 16;
    const int p  = px0 + px_l;
    const int pp = p + (p / WID) * 2 + 51;    // (h+1)*50 + (w+1)
    unsigned short* op = Xtp + (((size_t)tb * 4 + g) * PHW + pp) * 64 + cg;
    *(short8v*)op       = *(const short8v*)&t_[px_l][cg];
    *(short8v*)(op + 8) = *(const short8v*)&t_[px_l][cg + 8];
}

// ---- conv: round-6 memory plan; counted-vmcnt A pipeline + kh wave-stagger
__global__ __launch_bounds__(256, 2) void conv13_k(
    const unsigned short* __restrict__ Xtp, const unsigned short* __restrict__ At,
    const float* __restrict__ Bs, unsigned short* __restrict__ Y, int tb_base)
{
    __shared__ short ldsA[2][8192];    // 128 rows x 128B, double-buffered (32 KB)
    __shared__ short ldsB[19200];      // slab: 300 padded px x 128B (37.5 KB)

    const int tid = threadIdx.x;
    const int wv  = tid >> 6, ln = tid & 63;
    const int lr  = ln & 15,  lg = ln >> 4;
    const int wm  = wv >> 1,  wn = wv & 1;

    // bijective XCD swizzle, nwg=768 (q=96)
    const int orig = blockIdx.x;
    const int wg   = (orig & 7) * 96 + (orig >> 3);
    const int tb_l = wg / 24;
    const int rem  = wg - tb_l * 24;
    const int rt   = rem >> 1;           // row-tile 0..11 (4 image rows)
    const int by   = rem & 1;

    int boff[6];
    #pragma unroll
    for (int ni = 0; ni < 6; ++ni) {
        const int p = wn * 96 + ni * 16 + lr;
        const int r = p / 48, c = p - r * 48;
        boff[ni] = (r + 1) * 50 + (c + 1);
    }
    const int cx0 = ((lg << 4) ^ ((lr & 7) << 4)) >> 1;
    const int cx1 = ((64 | (lg << 4)) ^ ((lr & 7) << 4)) >> 1;

    const unsigned short* Asrc  = At + (size_t)by * 36 * 8192 + wv * 2048 + ln * 8;
    const unsigned short* slab0 = Xtp + (size_t)tb_l * 4 * PHW * 64 + (size_t)rt * 200 * 64;

    f32x4 acc[4][6];
    const f32x4 zero = {0.f, 0.f, 0.f, 0.f};
    #pragma unroll
    for (int i = 0; i < 4; ++i)
        #pragma unroll
        for (int j = 0; j < 6; ++j) acc[i][j] = zero;

    auto stageA = [&](int kt2) {                  // A(kt2) -> ldsA[kt2&1]
        const unsigned short* ap = Asrc + (size_t)kt2 * 8192;
        #pragma unroll
        for (int i = 0; i < 4; ++i)
            gload_lds16(ap + i * 512, &ldsA[kt2 & 1][wv * 2048 + i * 512]);
    };
    auto stage_slab = [&](int g) {
        const unsigned short* sg = slab0 + (size_t)g * PHW * 64;
        #pragma unroll
        for (int j = 0; j < 10; ++j) {
            const int cc = tid + 256 * j;
            if (cc < 2400) {
                const int p = cc >> 3, k = cc & 7;
                gload_lds16(sg + p * 64 + ((k ^ (p & 7)) << 3),
                            &ldsB[(wv * 64 + 256 * j) * 8]);
            }
        }
    };

    // prologue: slab(0) + A(0)
    stage_slab(0);
    stageA(0);
    asm volatile("s_waitcnt vmcnt(0)" ::: "memory");
    __builtin_amdgcn_sched_barrier(0);
    __builtin_amdgcn_s_barrier();

    for (int g = 0; g < 4; ++g) {
        #pragma unroll
        for (int tap = 0; tap < 9; ++tap) {
            const int kt2 = g * 9 + tap;
            const int cur = kt2 & 1;
            // (A) issue next A tile (stays in flight across the barrier)
            if (tap < 8 || g < 3) stageA(kt2 + 1);
            // (B) wait only for the 4 loads that filled ldsA[cur] (issued last tap)
            if (tap < 8) { asm volatile("s_waitcnt vmcnt(4)" ::: "memory"); }
            else         { asm volatile("s_waitcnt vmcnt(0)" ::: "memory"); }
            __builtin_amdgcn_sched_barrier(0);
            __builtin_amdgcn_s_barrier();             // (C) tile ready

            const int toff = (tap / 3 - 1) * 50 + (tap % 3 - 1);
            const int khf  = wm;                      // wave-pair kh stagger
            #pragma unroll
            for (int kk = 0; kk < 2; ++kk) {
                const int kh = khf ^ kk;
                const int cx = kh ? cx1 : cx0;
                short8v a_[4], b_[6];
                #pragma unroll
                for (int mi = 0; mi < 4; ++mi)
                    a_[mi] = *(const short8v*)&ldsA[cur][(wm * 64 + mi * 16 + lr) * 64 + cx];
                #pragma unroll
                for (int ni = 0; ni < 6; ++ni) {
                    const int sp = boff[ni] + toff;
                    b_[ni] = *(const short8v*)&ldsB[sp * 64 + ((((kh << 2) | lg) ^ (sp & 7)) << 3)];
                }
                __builtin_amdgcn_s_setprio(1);
                #pragma unroll
                for (int mi = 0; mi < 4; ++mi)
                    #pragma unroll
                    for (int ni = 0; ni < 6; ++ni)
                        acc[mi][ni] = __builtin_amdgcn_mfma_f32_16x16x32_bf16(
                            a_[mi], b_[ni], acc[mi][ni], 0, 0, 0);
                __builtin_amdgcn_s_setprio(0);
            }
            __builtin_amdgcn_s_barrier();             // (E) reads done

            if (tap == 8 && g < 3) {                  // slab for next ci-group
                stage_slab(g + 1);
                asm volatile("s_waitcnt vmcnt(0)" ::: "memory");
                __builtin_amdgcn_sched_barrier(0);
                __builtin_amdgcn_s_barrier();
            }
        }
    }

    // epilogue: D row=(lane>>4)*4+r (m), col=lane&15 (px)
    const int tbg   = tb_base + tb_l;
    const int nbase = rt * 192 + wn * 96;
    #pragma unroll
    for (int mi = 0; mi < 4; ++mi) {
        const int m = by * 128 + wm * 64 + mi * 16 + lg * 4;
        const f32x4 b4 = *(const f32x4*)&Bs[m];
        #pragma unroll
        for (int r = 0; r < 4; ++r) {
            unsigned short* yp = Y + ((size_t)tbg * CIN + m + r) * HWD + nbase;
            #pragma unroll
            for (int ni = 0; ni < 6; ++ni)
                yp[ni * 16 + lr] = f2bf(acc[mi][ni][r] + b4[r]);
        }
    }
}

// ---- LI scan in place on bf16 Y, 8 elems/thread (uint4, 16B/lane)
__global__ __launch_bounds__(256) void li_scan4_k(uint4* __restrict__ Y)
{
    const int n = blockIdx.x * 256 + threadIdx.x;   // uint4 index within slice
    float v[8], c[8];
    #pragma unroll
    for (int e = 0; e < 8; ++e) { v[e] = 0.f; c[e] = 0.f; }
    #pragma unroll
    for (int t = 0; t < 16; ++t) {
        const size_t idx = (size_t)t * (SLICE / 8) + n;
        uint4 u = Y[idx];
        float x[8] = { bf2f((unsigned short)(u.x & 0xffff)), bf2f((unsigned short)(u.x >> 16)),
                       bf2f((unsigned short)(u.y & 0xffff)), bf2f((unsigned short)(u.y >> 16)),
                       bf2f((unsigned short)(u.z & 0xffff)), bf2f((unsigned short)(u.z >> 16)),
                       bf2f((unsigned short)(u.w & 0xffff)), bf2f((unsigned short)(u.w >> 16)) };
        #pragma unroll
        for (int e = 0; e < 8; ++e) {
            v[e] = v[e] + 0.1f * ((0.0f - v[e]) + c[e]);
            c[e] = c[e] - 0.2f * c[e] + x[e];
        }
        u.x = (unsigned)f2bf(v[0]) | ((unsigned)f2bf(v[1]) << 16);
        u.y = (unsigned)f2bf(v[2]) | ((unsigned)f2bf(v[3]) << 16);
        u.z = (unsigned)f2bf(v[4]) | ((unsigned)f2bf(v[5]) << 16);
        u.w = (unsigned)f2bf(v[6]) | ((unsigned)f2bf(v[7]) << 16);
        Y[idx] = u;
    }
}

// ---- 1x1 heads, 2 pixels/thread
__global__ __launch_bounds__(256) void heads_k(
    const unsigned int* __restrict__ V,
    const float* __restrict__ bw, const float* __restrict__ bb,
    const float* __restrict__ cw, const float* __restrict__ cb,
    float* __restrict__ out)
{
    const int n = blockIdx.x * 256 + threadIdx.x;
    const int tb  = n / (HWD / 2);
    const int hw2 = n - tb * (HWD / 2);
    const unsigned int* vp = V + (size_t)tb * CIN * (HWD / 2) + hw2;

    float b0[12], b1[12], cl0[9], cl1[9];
    #pragma unroll
    for (int o = 0; o < 12; ++o) { b0[o] = bb[o]; b1[o] = bb[o]; }
    #pragma unroll
    for (int o = 0; o < 9;  ++o) { cl0[o] = cb[o]; cl1[o] = cb[o]; }

    for (int ci = 0; ci < CIN; ++ci) {
        const unsigned u = vp[(size_t)ci * (HWD / 2)];
        const float lo = bf2f((unsigned short)(u & 0xffff));
        const float hi = bf2f((unsigned short)(u >> 16));
        #pragma unroll
        for (int o = 0; o < 12; ++o) {
            const float w = bw[o * CIN + ci];
            b0[o] += lo * w; b1[o] += hi * w;
        }
        #pragma unroll
        for (int o = 0; o < 9; ++o) {
            const float w = cw[o * CIN + ci];
            cl0[o] += lo * w; cl1[o] += hi * w;
        }
    }

    const int hw = hw2 * 2;
    float* ob = out + (size_t)tb * 12 * HWD + hw;
    #pragma unroll
    for (int o = 0; o < 12; ++o) { ob[(size_t)o * HWD] = b0[o]; ob[(size_t)o * HWD + 1] = b1[o]; }
    float* oc = out + (size_t)12 * NTB * HWD + (size_t)tb * 9 * HWD + hw;
    #pragma unroll
    for (int o = 0; o < 9;  ++o) { oc[(size_t)o * HWD] = cl0[o]; oc[(size_t)o * HWD + 1] = cl1[o]; }
}

extern "C" void kernel_launch(void* const* d_in, const int* in_sizes, int n_in,
                              void* d_out, int out_size, void* d_ws, size_t ws_size,
                              hipStream_t stream)
{
    const float* X   = (const float*)d_in[0];  // (16,4,256,48,48)
    const float* cw3 = (const float*)d_in[1];  // (256,256,3,3)
    const float* cb3 = (const float*)d_in[2];  // (256,)
    const float* bw  = (const float*)d_in[3];
    const float* bb  = (const float*)d_in[4];
    const float* clw = (const float*)d_in[5];
    const float* clb = (const float*)d_in[6];
    float* out = (float*)d_out;

    unsigned short* Xtp = (unsigned short*)((char*)d_ws + WS_XT);
    unsigned short* At  = (unsigned short*)((char*)d_ws + WS_AT);
    unsigned short* Y   = (unsigned short*)((char*)d_ws + WS_Y);

    hipMemsetAsync(Xtp, 0, 40960000, stream);   // halo zeros (covers both halves)
    prep_w_k<<<288, 256, 0, stream>>>(cw3, At);

    for (int half = 0; half < 2; ++half) {
        const float* Xh = X + (size_t)half * 32 * CIN * HWD;
        prep_x_k<<<dim3(36, 4, 32), 256, 0, stream>>>(Xh, Xtp);
        conv13_k<<<768, 256, 0, stream>>>(Xtp, At, cb3, Y, half * 32);
    }

    li_scan4_k<<<SLICE / 2048, 256, 0, stream>>>((uint4*)Y);
    heads_k   <<<NTB * HWD / 512, 256, 0, stream>>>((const unsigned int*)Y,
                                                    bw, bb, clw, clb, out);
}

// Round 14
// 268.103 us; speedup vs baseline: 1.7459x; 1.7459x over previous
//
#include <hip/hip_runtime.h>

#define CIN    256
#define WID    48
#define HWD    2304            // 48*48
#define PHW    2500            // 50*50 padded
#define NTB    64              // ts(16) * b(4)
#define SLICE  (4*CIN*HWD)

// workspace (bytes); ws >= 150,994,944 known-safe
#define WS_XT  0               // Xtp half: 32*4*2500*64*2 = 40,960,000
#define WS_AT  40960000        // A-tiles : 2*36*8192*2   =  1,179,648
#define WS_Y   42139648        // Y bf16 [tb][px][co]: 64*2304*256*2 = 75,497,472

typedef __attribute__((ext_vector_type(8))) short short8v;  // 8 bf16
typedef __attribute__((ext_vector_type(4))) float f32x4;

__device__ __forceinline__ unsigned short f2bf(float f) {
    unsigned u = __float_as_uint(f);
    u = (u + 0x7fffu + ((u >> 16) & 1u)) >> 16;   // RNE
    return (unsigned short)u;
}
__device__ __forceinline__ float bf2f(unsigned short s) {
    return __uint_as_float(((unsigned)s) << 16);
}
__device__ __forceinline__ void gload_lds16(const void* g, void* l) {
    __builtin_amdgcn_global_load_lds(
        (const __attribute__((address_space(1))) unsigned int*)g,
        (__attribute__((address_space(3))) unsigned int*)l, 16, 0, 0);
}

// ---- prep_w: W fp32 -> At bf16, pre-swizzled LDS image, tile order kt2 = g*9 + tap
__global__ __launch_bounds__(256) void prep_w_k(const float* __restrict__ Wt,
                                                unsigned short* __restrict__ At)
{
    const int s = (blockIdx.x * 256 + threadIdx.x) * 8;   // short index < 589824
    const int tile = s >> 13;                 // by*36 + kt2
    const int row  = (s & 8191) >> 6;
    const int colb = (s & 63) * 2;            // byte col (16B-aligned)
    const int by = tile / 36, kt2 = tile - by * 36;
    const int g = kt2 / 9, tap = kt2 - g * 9;
    const int k0 = (colb ^ ((row & 7) << 4)) >> 1;   // elem 0..63, 8-aligned
    const int co = by * 128 + row;
    const float* wp = Wt + (size_t)co * 2304 + (g * 64 + k0) * 9 + tap;
    short8v v;
    #pragma unroll
    for (int j = 0; j < 8; ++j) v[j] = (short)f2bf(wp[j * 9]);
    *(short8v*)(At + s) = v;
}

// ---- prep_x: X fp32 [32tb][ci][px] -> Xtp bf16 [32tb][g][pp(2500)][64ci], halo stays zero
__global__ __launch_bounds__(256) void prep_x_k(const float* __restrict__ X,
                                                unsigned short* __restrict__ Xtp)
{
    __shared__ unsigned short t_[64][72];
    const int tid = threadIdx.x;
    const int px0 = blockIdx.x * 64;
    const int g   = blockIdx.y;               // ci group of 64
    const int tb  = blockIdx.z;

    const int ci_l = tid >> 2, pg = (tid & 3) * 16;
    const float* xp = X + ((size_t)tb * CIN + g * 64 + ci_l) * HWD + px0 + pg;
    #pragma unroll
    for (int q = 0; q < 4; ++q) {
        f32x4 v = *(const f32x4*)(xp + q * 4);
        #pragma unroll
        for (int e = 0; e < 4; ++e)
            t_[pg + q * 4 + e][ci_l] = f2bf(v[e]);
    }
    __syncthreads();
    const int px_l = tid >> 2, cg = (tid & 3) * 16;
    const int p  = px0 + px_l;
    const int pp = p + (p / WID) * 2 + 51;    // (h+1)*50 + (w+1)
    unsigned short* op = Xtp + (((size_t)tb * 4 + g) * PHW + pp) * 64 + cg;
    *(short8v*)op       = *(const short8v*)&t_[px_l][cg];
    *(short8v*)(op + 8) = *(const short8v*)&t_[px_l][cg + 8];
}

// ---- conv (r6/r12 proven K-loop); NEW epilogue: LDS transpose -> Y[tb][px][256co]
__global__ __launch_bounds__(256, 2) void conv14_k(
    const unsigned short* __restrict__ Xtp, const unsigned short* __restrict__ At,
    const float* __restrict__ Bs, unsigned short* __restrict__ Y, int tb_base)
{
    __shared__ short ldsA[2][8192];    // 128 rows x 128B, double-buffered (32 KB)
    __shared__ short ldsB[19200];      // slab: 300 padded px x 128B (37.5 KB)

    const int tid = threadIdx.x;
    const int wv  = tid >> 6, ln = tid & 63;
    const int lr  = ln & 15,  lg = ln >> 4;
    const int wm  = wv >> 1,  wn = wv & 1;

    // bijective XCD swizzle, nwg=768 (q=96)
    const int orig = blockIdx.x;
    const int wg   = (orig & 7) * 96 + (orig >> 3);
    const int tb_l = wg / 24;
    const int rem  = wg - tb_l * 24;
    const int rt   = rem >> 1;           // row-tile 0..11 (4 image rows)
    const int by   = rem & 1;

    int boff[6];
    #pragma unroll
    for (int ni = 0; ni < 6; ++ni) {
        const int p = wn * 96 + ni * 16 + lr;
        const int r = p / 48, c = p - r * 48;
        boff[ni] = (r + 1) * 50 + (c + 1);
    }
    const int cx0 = ((lg << 4) ^ ((lr & 7) << 4)) >> 1;
    const int cx1 = ((64 | (lg << 4)) ^ ((lr & 7) << 4)) >> 1;

    const unsigned short* Asrc  = At + (size_t)by * 36 * 8192 + wv * 2048 + ln * 8;
    const unsigned short* slab0 = Xtp + (size_t)tb_l * 4 * PHW * 64 + (size_t)rt * 200 * 64;

    f32x4 acc[4][6];
    const f32x4 zero = {0.f, 0.f, 0.f, 0.f};
    #pragma unroll
    for (int i = 0; i < 4; ++i)
        #pragma unroll
        for (int j = 0; j < 6; ++j) acc[i][j] = zero;

    for (int g = 0; g < 4; ++g) {
        // ---- stage B slab (once per ci-group): 2400 16B cells, pre-swizzled source
        const unsigned short* sg = slab0 + (size_t)g * PHW * 64;
        #pragma unroll
        for (int j = 0; j < 10; ++j) {
            const int cc = tid + 256 * j;
            if (cc < 2400) {
                const int p = cc >> 3, k = cc & 7;
                gload_lds16(sg + p * 64 + ((k ^ (p & 7)) << 3),
                            &ldsB[(wv * 64 + 256 * j) * 8]);
            }
        }
        // ---- stage A tile (g, tap0) into buf 0
        const unsigned short* ag = Asrc + (size_t)g * 9 * 8192;
        #pragma unroll
        for (int i = 0; i < 4; ++i)
            gload_lds16(ag + i * 512, &ldsA[0][wv * 2048 + i * 512]);
        asm volatile("s_waitcnt vmcnt(0)" ::: "memory");
        __builtin_amdgcn_sched_barrier(0);
        __builtin_amdgcn_s_barrier();

        #pragma unroll
        for (int tap = 0; tap < 9; ++tap) {
            const int cur = tap & 1;
            if (tap < 8) {                      // prefetch next A tile
                const unsigned short* an = ag + (size_t)(tap + 1) * 8192;
                #pragma unroll
                for (int i = 0; i < 4; ++i)
                    gload_lds16(an + i * 512, &ldsA[cur ^ 1][wv * 2048 + i * 512]);
            }
            const int toff = (tap / 3 - 1) * 50 + (tap % 3 - 1);
            #pragma unroll
            for (int kh = 0; kh < 2; ++kh) {
                const int cx = kh ? cx1 : cx0;
                short8v a_[4], b_[6];
                #pragma unroll
                for (int mi = 0; mi < 4; ++mi)
                    a_[mi] = *(const short8v*)&ldsA[cur][(wm * 64 + mi * 16 + lr) * 64 + cx];
                #pragma unroll
                for (int ni = 0; ni < 6; ++ni) {
                    const int sp = boff[ni] + toff;
                    b_[ni] = *(const short8v*)&ldsB[sp * 64 + ((((kh << 2) | lg) ^ (sp & 7)) << 3)];
                }
                __builtin_amdgcn_s_setprio(1);
                #pragma unroll
                for (int mi = 0; mi < 4; ++mi)
                    #pragma unroll
                    for (int ni = 0; ni < 6; ++ni)
                        acc[mi][ni] = __builtin_amdgcn_mfma_f32_16x16x32_bf16(
                            a_[mi], b_[ni], acc[mi][ni], 0, 0, 0);
                __builtin_amdgcn_s_setprio(0);
            }
            asm volatile("s_waitcnt vmcnt(0)" ::: "memory");   // A(tap+1): 4 loads, L2-warm
            __builtin_amdgcn_sched_barrier(0);
            __builtin_amdgcn_s_barrier();
        }
    }

    // ---- epilogue: acc (+bias) -> bf16 -> swizzled LDS tiles -> Y[tb][px][co]
    short* t0 = ldsB;                 // wn==0 tile: [96 px][128 co] shorts, swizzled
    short* t1 = &ldsA[0][0];          // wn==1 tile
    short* dst = wn ? t1 : t0;
    #pragma unroll
    for (int mi = 0; mi < 4; ++mi) {
        const int m = by * 128 + wm * 64 + mi * 16 + lg * 4;
        const f32x4 b4 = *(const f32x4*)&Bs[m];
        #pragma unroll
        for (int ni = 0; ni < 6; ++ni) {
            const int pl = ni * 16 + lr;                    // 0..95
            const unsigned short h0 = f2bf(acc[mi][ni][0] + b4[0]);
            const unsigned short h1 = f2bf(acc[mi][ni][1] + b4[1]);
            const unsigned short h2 = f2bf(acc[mi][ni][2] + b4[2]);
            const unsigned short h3 = f2bf(acc[mi][ni][3] + b4[3]);
            const int co = wm * 64 + mi * 16 + lg * 4;      // 0..127 within by-half
            uint2 u;
            u.x = (unsigned)h0 | ((unsigned)h1 << 16);
            u.y = (unsigned)h2 | ((unsigned)h3 << 16);
            *(uint2*)&dst[pl * 128 + (co ^ ((pl & 7) << 3))] = u;
        }
    }
    __syncthreads();
    const int tbg = tb_base + tb_l;
    #pragma unroll
    for (int j = 0; j < 12; ++j) {
        const int pass = (j >= 6);
        const int tsk  = tid + 256 * (pass ? j - 6 : j);    // 0..1535
        const int pl   = tsk >> 4, oct = tsk & 15;
        const short* src = pass ? t1 : t0;
        short8v val = *(const short8v*)&src[pl * 128 + ((oct * 8) ^ ((pl & 7) << 3))];
        const int px = rt * 192 + pass * 96 + pl;
        *(short8v*)&Y[((size_t)tbg * HWD + px) * 256 + by * 128 + oct * 8] = val;
    }
}

// ---- fused LI scan + 1x1 heads. Y[tb][px][256co] bf16, out fp32.
// grid (72 px-tiles, 4 b); thread owns (px_l = tid>>3, ci = (tid&7)*32 .. +32)
__global__ __launch_bounds__(256) void liheads_k(
    const unsigned short* __restrict__ Y,
    const float* __restrict__ bw, const float* __restrict__ bb,
    const float* __restrict__ cw, const float* __restrict__ cb,
    float* __restrict__ out)
{
    __shared__ short Wl[32 * 256];          // [32 o][256 ci] swizzled (16 KB)
    __shared__ short Vl[32 * 256];          // [32 px][256 ci] swizzled (16 KB)

    const int tid = threadIdx.x;
    const int ln  = tid & 63;
    const int wv  = tid >> 6;
    const int mq  = wv & 1, nq = wv >> 1;
    const int px0 = blockIdx.x * 32;
    const int b   = blockIdx.y;

    // stage padded head-weight tile (rows: 0..11 box, 12..20 cls, 21..31 zero)
    {
        const int row = tid >> 3;
        const int cb8 = (tid & 7) * 32;
        #pragma unroll
        for (int j = 0; j < 4; ++j) {
            const int ci = cb8 + j * 8;
            short8v v8;
            if (row < 12) {
                #pragma unroll
                for (int e = 0; e < 8; ++e) v8[e] = (short)f2bf(bw[row * 256 + ci + e]);
            } else if (row < 21) {
                #pragma unroll
                for (int e = 0; e < 8; ++e) v8[e] = (short)f2bf(cw[(row - 12) * 256 + ci + e]);
            } else {
                #pragma unroll
                for (int e = 0; e < 8; ++e) v8[e] = 0;
            }
            *(short8v*)&Wl[row * 256 + (ci ^ ((row & 7) << 3))] = v8;
        }
    }
    __syncthreads();

    // preload A-frags (8 K-steps) for this wave's o-quad
    const int arow = mq * 16 + (ln & 15);
    const int kb   = (ln >> 4) * 8;
    short8v af[8];
    #pragma unroll
    for (int ks = 0; ks < 8; ++ks)
        af[ks] = *(const short8v*)&Wl[arow * 256 + ((ks * 32 + kb) ^ ((arow & 7) << 3))];

    float bias[4];
    #pragma unroll
    for (int r = 0; r < 4; ++r) {
        const int o = mq * 16 + (ln >> 4) * 4 + r;
        bias[r] = (o < 12) ? bb[o] : (o < 21 ? cb[o - 12] : 0.f);
    }

    const int px_l = tid >> 3, q8 = tid & 7;
    const unsigned short* xbase = Y + ((size_t)b * HWD + px0 + px_l) * 256 + q8 * 32;

    float v[32], cc[32];
    #pragma unroll
    for (int e = 0; e < 32; ++e) { v[e] = 0.f; cc[e] = 0.f; }

    uint4 xq[4];
    #pragma unroll
    for (int i = 0; i < 4; ++i) xq[i] = *(const uint4*)(xbase + i * 8);

    const int brow = nq * 16 + (ln & 15);
    const int px   = px0 + nq * 16 + (ln & 15);

    for (int t = 0; t < 16; ++t) {
        // LI update + pack v->bf16 into Vl
        #pragma unroll
        for (int i = 0; i < 4; ++i) {
            const unsigned uu0 = xq[i].x, uu1 = xq[i].y, uu2 = xq[i].z, uu3 = xq[i].w;
            const unsigned uus[4] = {uu0, uu1, uu2, uu3};
            unsigned outp[4];
            #pragma unroll
            for (int p = 0; p < 4; ++p) {
                const int e = i * 8 + p * 2;
                const float x0 = bf2f((unsigned short)(uus[p] & 0xffff));
                const float x1 = bf2f((unsigned short)(uus[p] >> 16));
                v[e]     += 0.1f * (cc[e]     - v[e]);
                v[e + 1] += 0.1f * (cc[e + 1] - v[e + 1]);
                cc[e]     = cc[e]     - 0.2f * cc[e]     + x0;
                cc[e + 1] = cc[e + 1] - 0.2f * cc[e + 1] + x1;
                outp[p] = (unsigned)f2bf(v[e]) | ((unsigned)f2bf(v[e + 1]) << 16);
            }
            uint4 w4; w4.x = outp[0]; w4.y = outp[1]; w4.z = outp[2]; w4.w = outp[3];
            *(uint4*)&Vl[px_l * 256 + ((q8 * 32 + i * 8) ^ ((px_l & 7) << 3))] = w4;
        }
        if (t < 15) {                         // prefetch next timestep (covers MFMA phase)
            const unsigned short* nb = xbase + (size_t)(t + 1) * SLICE;
            #pragma unroll
            for (int i = 0; i < 4; ++i) xq[i] = *(const uint4*)(nb + i * 8);
        }
        __syncthreads();

        f32x4 acc = {0.f, 0.f, 0.f, 0.f};
        #pragma unroll
        for (int ks = 0; ks < 8; ++ks) {
            short8v bf = *(const short8v*)&Vl[brow * 256 + ((ks * 32 + kb) ^ ((brow & 7) << 3))];
            acc = __builtin_amdgcn_mfma_f32_16x16x32_bf16(af[ks], bf, acc, 0, 0, 0);
        }
        #pragma unroll
        for (int r = 0; r < 4; ++r) {
            const int o = mq * 16 + (ln >> 4) * 4 + r;
            const float val = acc[r] + bias[r];
            if (o < 12)
                out[(((size_t)t * 4 + b) * 12 + o) * HWD + px] = val;
            else if (o < 21)
                out[(size_t)1769472 + (((size_t)t * 4 + b) * 9 + (o - 12)) * HWD + px] = val;
        }
        __syncthreads();                      // Vl consumed before next t's writes
    }
}

extern "C" void kernel_launch(void* const* d_in, const int* in_sizes, int n_in,
                              void* d_out, int out_size, void* d_ws, size_t ws_size,
                              hipStream_t stream)
{
    const float* X   = (const float*)d_in[0];  // (16,4,256,48,48)
    const float* cw3 = (const float*)d_in[1];  // (256,256,3,3)
    const float* cb3 = (const float*)d_in[2];  // (256,)
    const float* bw  = (const float*)d_in[3];
    const float* bb  = (const float*)d_in[4];
    const float* clw = (const float*)d_in[5];
    const float* clb = (const float*)d_in[6];
    float* out = (float*)d_out;

    unsigned short* Xtp = (unsigned short*)((char*)d_ws + WS_XT);
    unsigned short* At  = (unsigned short*)((char*)d_ws + WS_AT);
    unsigned short* Y   = (unsigned short*)((char*)d_ws + WS_Y);

    hipMemsetAsync(Xtp, 0, 40960000, stream);   // halo zeros (covers both halves)
    prep_w_k<<<288, 256, 0, stream>>>(cw3, At);

    for (int half = 0; half < 2; ++half) {
        const float* Xh = X + (size_t)half * 32 * CIN * HWD;
        prep_x_k<<<dim3(36, 4, 32), 256, 0, stream>>>(Xh, Xtp);
        conv14_k<<<768, 256, 0, stream>>>(Xtp, At, cb3, Y, half * 32);
    }

    liheads_k<<<dim3(72, 4), 256, 0, stream>>>(Y, bw, bb, clw, clb, out);
}

// Round 15
// 265.814 us; speedup vs baseline: 1.7609x; 1.0086x over previous
//
#include <hip/hip_runtime.h>

#define CIN    256
#define WID    48
#define HWD    2304            // 48*48
#define PHW    2500            // 50*50 padded
#define NTB    64              // ts(16) * b(4)
#define SLICE  (4*CIN*HWD)

// workspace (bytes); ws >= 150,994,944 known-safe
#define WS_XT  0               // Xtp half: 32*4*2500*64*2 = 40,960,000
#define WS_AT  40960000        // A-tiles : 2*36*8192*2   =  1,179,648
#define WS_Y   42139648        // Y bf16 [tb][px][co]: 64*2304*256*2 = 75,497,472

typedef __attribute__((ext_vector_type(8))) short short8v;  // 8 bf16
typedef __attribute__((ext_vector_type(4))) float f32x4;

__device__ __forceinline__ unsigned short f2bf(float f) {
    unsigned u = __float_as_uint(f);
    u = (u + 0x7fffu + ((u >> 16) & 1u)) >> 16;   // RNE
    return (unsigned short)u;
}
__device__ __forceinline__ float bf2f(unsigned short s) {
    return __uint_as_float(((unsigned)s) << 16);
}
__device__ __forceinline__ void gload_lds16(const void* g, void* l) {
    __builtin_amdgcn_global_load_lds(
        (const __attribute__((address_space(1))) unsigned int*)g,
        (__attribute__((address_space(3))) unsigned int*)l, 16, 0, 0);
}

// ---- halo_zero: zero only the 196 halo cells per (tb,g) of Xtp (3.2 MB vs 41 MB memset)
__global__ __launch_bounds__(256) void halo_zero_k(unsigned short* __restrict__ Xtp)
{
    const int tbg = blockIdx.x;          // 0..127 = tb*4 + g
    const int tid = threadIdx.x;
    const short8v z = {0, 0, 0, 0, 0, 0, 0, 0};
    #pragma unroll
    for (int j = 0; j < 7; ++j) {
        const int task = tid + 256 * j;  // 196 cells * 8 chunks = 1568
        if (task < 1568) {
            const int c = task >> 3, k = task & 7;
            int pp;
            if (c < 50)       pp = c;                                   // row 0
            else if (c < 100) pp = 2450 + (c - 50);                     // row 49
            else { const int e = c - 100; pp = (1 + (e >> 1)) * 50 + (e & 1) * 49; } // cols 0/49
            *(short8v*)&Xtp[((size_t)tbg * PHW + pp) * 64 + k * 8] = z;
        }
    }
}

// ---- prep_w: W fp32 -> At bf16, pre-swizzled LDS image, tile order kt2 = g*9 + tap
__global__ __launch_bounds__(256) void prep_w_k(const float* __restrict__ Wt,
                                                unsigned short* __restrict__ At)
{
    const int s = (blockIdx.x * 256 + threadIdx.x) * 8;   // short index < 589824
    const int tile = s >> 13;                 // by*36 + kt2
    const int row  = (s & 8191) >> 6;
    const int colb = (s & 63) * 2;            // byte col (16B-aligned)
    const int by = tile / 36, kt2 = tile - by * 36;
    const int g = kt2 / 9, tap = kt2 - g * 9;
    const int k0 = (colb ^ ((row & 7) << 4)) >> 1;   // elem 0..63, 8-aligned
    const int co = by * 128 + row;
    const float* wp = Wt + (size_t)co * 2304 + (g * 64 + k0) * 9 + tap;
    short8v v;
    #pragma unroll
    for (int j = 0; j < 8; ++j) v[j] = (short)f2bf(wp[j * 9]);
    *(short8v*)(At + s) = v;
}

// ---- prep_x: X fp32 [32tb][ci][px] -> Xtp bf16 [32tb][g][pp(2500)][64ci], halo stays zero
__global__ __launch_bounds__(256) void prep_x_k(const float* __restrict__ X,
                                                unsigned short* __restrict__ Xtp)
{
    __shared__ unsigned short t_[64][72];
    const int tid = threadIdx.x;
    const int px0 = blockIdx.x * 64;
    const int g   = blockIdx.y;               // ci group of 64
    const int tb  = blockIdx.z;

    const int ci_l = tid >> 2, pg = (tid & 3) * 16;
    const float* xp = X + ((size_t)tb * CIN + g * 64 + ci_l) * HWD + px0 + pg;
    #pragma unroll
    for (int q = 0; q < 4; ++q) {
        f32x4 v = *(const f32x4*)(xp + q * 4);
        #pragma unroll
        for (int e = 0; e < 4; ++e)
            t_[pg + q * 4 + e][ci_l] = f2bf(v[e]);
    }
    __syncthreads();
    const int px_l = tid >> 2, cg = (tid & 3) * 16;
    const int p  = px0 + px_l;
    const int pp = p + (p / WID) * 2 + 51;    // (h+1)*50 + (w+1)
    unsigned short* op = Xtp + (((size_t)tb * 4 + g) * PHW + pp) * 64 + cg;
    *(short8v*)op       = *(const short8v*)&t_[px_l][cg];
    *(short8v*)(op + 8) = *(const short8v*)&t_[px_l][cg + 8];
}

// ---- conv (r6/r12 proven K-loop); epilogue: LDS transpose -> Y[tb][px][256co]
__global__ __launch_bounds__(256, 2) void conv14_k(
    const unsigned short* __restrict__ Xtp, const unsigned short* __restrict__ At,
    const float* __restrict__ Bs, unsigned short* __restrict__ Y, int tb_base)
{
    __shared__ short ldsA[2][8192];    // 128 rows x 128B, double-buffered (32 KB)
    __shared__ short ldsB[19200];      // slab: 300 padded px x 128B (37.5 KB)

    const int tid = threadIdx.x;
    const int wv  = tid >> 6, ln = tid & 63;
    const int lr  = ln & 15,  lg = ln >> 4;
    const int wm  = wv >> 1,  wn = wv & 1;

    // bijective XCD swizzle, nwg=768 (q=96)
    const int orig = blockIdx.x;
    const int wg   = (orig & 7) * 96 + (orig >> 3);
    const int tb_l = wg / 24;
    const int rem  = wg - tb_l * 24;
    const int rt   = rem >> 1;           // row-tile 0..11 (4 image rows)
    const int by   = rem & 1;

    int boff[6];
    #pragma unroll
    for (int ni = 0; ni < 6; ++ni) {
        const int p = wn * 96 + ni * 16 + lr;
        const int r = p / 48, c = p - r * 48;
        boff[ni] = (r + 1) * 50 + (c + 1);
    }
    const int cx0 = ((lg << 4) ^ ((lr & 7) << 4)) >> 1;
    const int cx1 = ((64 | (lg << 4)) ^ ((lr & 7) << 4)) >> 1;

    const unsigned short* Asrc  = At + (size_t)by * 36 * 8192 + wv * 2048 + ln * 8;
    const unsigned short* slab0 = Xtp + (size_t)tb_l * 4 * PHW * 64 + (size_t)rt * 200 * 64;

    f32x4 acc[4][6];
    const f32x4 zero = {0.f, 0.f, 0.f, 0.f};
    #pragma unroll
    for (int i = 0; i < 4; ++i)
        #pragma unroll
        for (int j = 0; j < 6; ++j) acc[i][j] = zero;

    for (int g = 0; g < 4; ++g) {
        // ---- stage B slab (once per ci-group): 2400 16B cells, pre-swizzled source
        const unsigned short* sg = slab0 + (size_t)g * PHW * 64;
        #pragma unroll
        for (int j = 0; j < 10; ++j) {
            const int cc = tid + 256 * j;
            if (cc < 2400) {
                const int p = cc >> 3, k = cc & 7;
                gload_lds16(sg + p * 64 + ((k ^ (p & 7)) << 3),
                            &ldsB[(wv * 64 + 256 * j) * 8]);
            }
        }
        // ---- stage A tile (g, tap0) into buf 0
        const unsigned short* ag = Asrc + (size_t)g * 9 * 8192;
        #pragma unroll
        for (int i = 0; i < 4; ++i)
            gload_lds16(ag + i * 512, &ldsA[0][wv * 2048 + i * 512]);
        asm volatile("s_waitcnt vmcnt(0)" ::: "memory");
        __builtin_amdgcn_sched_barrier(0);
        __builtin_amdgcn_s_barrier();

        #pragma unroll
        for (int tap = 0; tap < 9; ++tap) {
            const int cur = tap & 1;
            if (tap < 8) {                      // prefetch next A tile
                const unsigned short* an = ag + (size_t)(tap + 1) * 8192;
                #pragma unroll
                for (int i = 0; i < 4; ++i)
                    gload_lds16(an + i * 512, &ldsA[cur ^ 1][wv * 2048 + i * 512]);
            }
            const int toff = (tap / 3 - 1) * 50 + (tap % 3 - 1);
            #pragma unroll
            for (int kh = 0; kh < 2; ++kh) {
                const int cx = kh ? cx1 : cx0;
                short8v a_[4], b_[6];
                #pragma unroll
                for (int mi = 0; mi < 4; ++mi)
                    a_[mi] = *(const short8v*)&ldsA[cur][(wm * 64 + mi * 16 + lr) * 64 + cx];
                #pragma unroll
                for (int ni = 0; ni < 6; ++ni) {
                    const int sp = boff[ni] + toff;
                    b_[ni] = *(const short8v*)&ldsB[sp * 64 + ((((kh << 2) | lg) ^ (sp & 7)) << 3)];
                }
                __builtin_amdgcn_s_setprio(1);
                #pragma unroll
                for (int mi = 0; mi < 4; ++mi)
                    #pragma unroll
                    for (int ni = 0; ni < 6; ++ni)
                        acc[mi][ni] = __builtin_amdgcn_mfma_f32_16x16x32_bf16(
                            a_[mi], b_[ni], acc[mi][ni], 0, 0, 0);
                __builtin_amdgcn_s_setprio(0);
            }
            asm volatile("s_waitcnt vmcnt(0)" ::: "memory");   // A(tap+1): 4 loads, L2-warm
            __builtin_amdgcn_sched_barrier(0);
            __builtin_amdgcn_s_barrier();
        }
    }

    // ---- epilogue: acc (+bias) -> bf16 -> swizzled LDS tiles -> Y[tb][px][co]
    short* t0 = ldsB;                 // wn==0 tile: [96 px][128 co] shorts, swizzled
    short* t1 = &ldsA[0][0];          // wn==1 tile
    short* dst = wn ? t1 : t0;
    #pragma unroll
    for (int mi = 0; mi < 4; ++mi) {
        const int m = by * 128 + wm * 64 + mi * 16 + lg * 4;
        const f32x4 b4 = *(const f32x4*)&Bs[m];
        #pragma unroll
        for (int ni = 0; ni < 6; ++ni) {
            const int pl = ni * 16 + lr;                    // 0..95
            const unsigned short h0 = f2bf(acc[mi][ni][0] + b4[0]);
            const unsigned short h1 = f2bf(acc[mi][ni][1] + b4[1]);
            const unsigned short h2 = f2bf(acc[mi][ni][2] + b4[2]);
            const unsigned short h3 = f2bf(acc[mi][ni][3] + b4[3]);
            const int co = wm * 64 + mi * 16 + lg * 4;      // 0..127 within by-half
            uint2 u;
            u.x = (unsigned)h0 | ((unsigned)h1 << 16);
            u.y = (unsigned)h2 | ((unsigned)h3 << 16);
            *(uint2*)&dst[pl * 128 + (co ^ ((pl & 7) << 3))] = u;
        }
    }
    __syncthreads();
    const int tbg = tb_base + tb_l;
    #pragma unroll
    for (int j = 0; j < 12; ++j) {
        const int pass = (j >= 6);
        const int tsk  = tid + 256 * (pass ? j - 6 : j);    // 0..1535
        const int pl   = tsk >> 4, oct = tsk & 15;
        const short* src = pass ? t1 : t0;
        short8v val = *(const short8v*)&src[pl * 128 + ((oct * 8) ^ ((pl & 7) << 3))];
        const int px = rt * 192 + pass * 96 + pl;
        *(short8v*)&Y[((size_t)tbg * HWD + px) * 256 + by * 128 + oct * 8] = val;
    }
}

// ---- fused LI scan + 1x1 heads. Y[tb][px][256co] bf16, out fp32.
__global__ __launch_bounds__(256) void liheads_k(
    const unsigned short* __restrict__ Y,
    const float* __restrict__ bw, const float* __restrict__ bb,
    const float* __restrict__ cw, const float* __restrict__ cb,
    float* __restrict__ out)
{
    __shared__ short Wl[32 * 256];          // [32 o][256 ci] swizzled (16 KB)
    __shared__ short Vl[32 * 256];          // [32 px][256 ci] swizzled (16 KB)

    const int tid = threadIdx.x;
    const int ln  = tid & 63;
    const int wv  = tid >> 6;
    const int mq  = wv & 1, nq = wv >> 1;
    const int px0 = blockIdx.x * 32;
    const int b   = blockIdx.y;

    // stage padded head-weight tile (rows: 0..11 box, 12..20 cls, 21..31 zero)
    {
        const int row = tid >> 3;
        const int cb8 = (tid & 7) * 32;
        #pragma unroll
        for (int j = 0; j < 4; ++j) {
            const int ci = cb8 + j * 8;
            short8v v8;
            if (row < 12) {
                #pragma unroll
                for (int e = 0; e < 8; ++e) v8[e] = (short)f2bf(bw[row * 256 + ci + e]);
            } else if (row < 21) {
                #pragma unroll
                for (int e = 0; e < 8; ++e) v8[e] = (short)f2bf(cw[(row - 12) * 256 + ci + e]);
            } else {
                #pragma unroll
                for (int e = 0; e < 8; ++e) v8[e] = 0;
            }
            *(short8v*)&Wl[row * 256 + (ci ^ ((row & 7) << 3))] = v8;
        }
    }
    __syncthreads();

    // preload A-frags (8 K-steps) for this wave's o-quad
    const int arow = mq * 16 + (ln & 15);
    const int kb   = (ln >> 4) * 8;
    short8v af[8];
    #pragma unroll
    for (int ks = 0; ks < 8; ++ks)
        af[ks] = *(const short8v*)&Wl[arow * 256 + ((ks * 32 + kb) ^ ((arow & 7) << 3))];

    float bias[4];
    #pragma unroll
    for (int r = 0; r < 4; ++r) {
        const int o = mq * 16 + (ln >> 4) * 4 + r;
        bias[r] = (o < 12) ? bb[o] : (o < 21 ? cb[o - 12] : 0.f);
    }

    const int px_l = tid >> 3, q8 = tid & 7;
    const unsigned short* xbase = Y + ((size_t)b * HWD + px0 + px_l) * 256 + q8 * 32;

    float v[32], cc[32];
    #pragma unroll
    for (int e = 0; e < 32; ++e) { v[e] = 0.f; cc[e] = 0.f; }

    uint4 xq[4];
    #pragma unroll
    for (int i = 0; i < 4; ++i) xq[i] = *(const uint4*)(xbase + i * 8);

    const int brow = nq * 16 + (ln & 15);
    const int px   = px0 + nq * 16 + (ln & 15);

    for (int t = 0; t < 16; ++t) {
        // LI update + pack v->bf16 into Vl
        #pragma unroll
        for (int i = 0; i < 4; ++i) {
            const unsigned uu0 = xq[i].x, uu1 = xq[i].y, uu2 = xq[i].z, uu3 = xq[i].w;
            const unsigned uus[4] = {uu0, uu1, uu2, uu3};
            unsigned outp[4];
            #pragma unroll
            for (int p = 0; p < 4; ++p) {
                const int e = i * 8 + p * 2;
                const float x0 = bf2f((unsigned short)(uus[p] & 0xffff));
                const float x1 = bf2f((unsigned short)(uus[p] >> 16));
                v[e]     += 0.1f * (cc[e]     - v[e]);
                v[e + 1] += 0.1f * (cc[e + 1] - v[e + 1]);
                cc[e]     = cc[e]     - 0.2f * cc[e]     + x0;
                cc[e + 1] = cc[e + 1] - 0.2f * cc[e + 1] + x1;
                outp[p] = (unsigned)f2bf(v[e]) | ((unsigned)f2bf(v[e + 1]) << 16);
            }
            uint4 w4; w4.x = outp[0]; w4.y = outp[1]; w4.z = outp[2]; w4.w = outp[3];
            *(uint4*)&Vl[px_l * 256 + ((q8 * 32 + i * 8) ^ ((px_l & 7) << 3))] = w4;
        }
        if (t < 15) {                         // prefetch next timestep (covers MFMA phase)
            const unsigned short* nb = xbase + (size_t)(t + 1) * SLICE;
            #pragma unroll
            for (int i = 0; i < 4; ++i) xq[i] = *(const uint4*)(nb + i * 8);
        }
        __syncthreads();

        f32x4 acc = {0.f, 0.f, 0.f, 0.f};
        #pragma unroll
        for (int ks = 0; ks < 8; ++ks) {
            short8v bf = *(const short8v*)&Vl[brow * 256 + ((ks * 32 + kb) ^ ((brow & 7) << 3))];
            acc = __builtin_amdgcn_mfma_f32_16x16x32_bf16(af[ks], bf, acc, 0, 0, 0);
        }
        #pragma unroll
        for (int r = 0; r < 4; ++r) {
            const int o = mq * 16 + (ln >> 4) * 4 + r;
            const float val = acc[r] + bias[r];
            if (o < 12)
                out[(((size_t)t * 4 + b) * 12 + o) * HWD + px] = val;
            else if (o < 21)
                out[(size_t)1769472 + (((size_t)t * 4 + b) * 9 + (o - 12)) * HWD + px] = val;
        }
        __syncthreads();                      // Vl consumed before next t's writes
    }
}

extern "C" void kernel_launch(void* const* d_in, const int* in_sizes, int n_in,
                              void* d_out, int out_size, void* d_ws, size_t ws_size,
                              hipStream_t stream)
{
    const float* X   = (const float*)d_in[0];  // (16,4,256,48,48)
    const float* cw3 = (const float*)d_in[1];  // (256,256,3,3)
    const float* cb3 = (const float*)d_in[2];  // (256,)
    const float* bw  = (const float*)d_in[3];
    const float* bb  = (const float*)d_in[4];
    const float* clw = (const float*)d_in[5];
    const float* clb = (const float*)d_in[6];
    float* out = (float*)d_out;

    unsigned short* Xtp = (unsigned short*)((char*)d_ws + WS_XT);
    unsigned short* At  = (unsigned short*)((char*)d_ws + WS_AT);
    unsigned short* Y   = (unsigned short*)((char*)d_ws + WS_Y);

    halo_zero_k<<<128, 256, 0, stream>>>(Xtp);  // 3.2 MB halo zeros (both halves)
    prep_w_k<<<288, 256, 0, stream>>>(cw3, At);

    for (int half = 0; half < 2; ++half) {
        const float* Xh = X + (size_t)half * 32 * CIN * HWD;
        prep_x_k<<<dim3(36, 4, 32), 256, 0, stream>>>(Xh, Xtp);
        conv14_k<<<768, 256, 0, stream>>>(Xtp, At, cb3, Y, half * 32);
    }

    liheads_k<<<dim3(72, 4), 256, 0, stream>>>(Y, bw, bb, clw, clb, out);
}

// Round 16
// 262.624 us; speedup vs baseline: 1.7823x; 1.0121x over previous
//
#include <hip/hip_runtime.h>

#define CIN    256
#define WID    48
#define HWD    2304            // 48*48
#define PHW    2500            // 50*50 padded
#define NTB    64              // ts(16) * b(4)
#define SLICE  (4*CIN*HWD)

// workspace (bytes); ws >= 150,994,944 known-safe
#define WS_XT  0               // Xtp half: 32*4*2500*64*2 = 40,960,000
#define WS_AT  40960000        // A-tiles : 2*36*8192*2   =  1,179,648
#define WS_Y   42139648        // Y bf16 [tb][px][co]: 64*2304*256*2 = 75,497,472

typedef __attribute__((ext_vector_type(8)))  short short8v;   // 8 bf16
typedef __attribute__((ext_vector_type(4)))  float f32x4;
typedef __attribute__((ext_vector_type(16))) float f32x16;

__device__ __forceinline__ unsigned short f2bf(float f) {
    unsigned u = __float_as_uint(f);
    u = (u + 0x7fffu + ((u >> 16) & 1u)) >> 16;   // RNE
    return (unsigned short)u;
}
__device__ __forceinline__ float bf2f(unsigned short s) {
    return __uint_as_float(((unsigned)s) << 16);
}
__device__ __forceinline__ void gload_lds16(const void* g, void* l) {
    __builtin_amdgcn_global_load_lds(
        (const __attribute__((address_space(1))) unsigned int*)g,
        (__attribute__((address_space(3))) unsigned int*)l, 16, 0, 0);
}

// ---- halo_zero: zero only the 196 halo cells per (tb,g) of Xtp
__global__ __launch_bounds__(256) void halo_zero_k(unsigned short* __restrict__ Xtp)
{
    const int tbg = blockIdx.x;          // 0..127 = tb*4 + g
    const int tid = threadIdx.x;
    const short8v z = {0, 0, 0, 0, 0, 0, 0, 0};
    #pragma unroll
    for (int j = 0; j < 7; ++j) {
        const int task = tid + 256 * j;  // 196 cells * 8 chunks = 1568
        if (task < 1568) {
            const int c = task >> 3, k = task & 7;
            int pp;
            if (c < 50)       pp = c;                                   // row 0
            else if (c < 100) pp = 2450 + (c - 50);                     // row 49
            else { const int e = c - 100; pp = (1 + (e >> 1)) * 50 + (e & 1) * 49; } // cols 0/49
            *(short8v*)&Xtp[((size_t)tbg * PHW + pp) * 64 + k * 8] = z;
        }
    }
}

// ---- prep_w: W fp32 -> At bf16, pre-swizzled LDS image, tile order kt2 = g*9 + tap
__global__ __launch_bounds__(256) void prep_w_k(const float* __restrict__ Wt,
                                                unsigned short* __restrict__ At)
{
    const int s = (blockIdx.x * 256 + threadIdx.x) * 8;   // short index < 589824
    const int tile = s >> 13;                 // by*36 + kt2
    const int row  = (s & 8191) >> 6;
    const int colb = (s & 63) * 2;            // byte col (16B-aligned)
    const int by = tile / 36, kt2 = tile - by * 36;
    const int g = kt2 / 9, tap = kt2 - g * 9;
    const int k0 = (colb ^ ((row & 7) << 4)) >> 1;   // elem 0..63, 8-aligned
    const int co = by * 128 + row;
    const float* wp = Wt + (size_t)co * 2304 + (g * 64 + k0) * 9 + tap;
    short8v v;
    #pragma unroll
    for (int j = 0; j < 8; ++j) v[j] = (short)f2bf(wp[j * 9]);
    *(short8v*)(At + s) = v;
}

// ---- prep_x: X fp32 [32tb][ci][px] -> Xtp bf16 [32tb][g][pp(2500)][64ci], halo stays zero
__global__ __launch_bounds__(256) void prep_x_k(const float* __restrict__ X,
                                                unsigned short* __restrict__ Xtp)
{
    __shared__ unsigned short t_[64][72];
    const int tid = threadIdx.x;
    const int px0 = blockIdx.x * 64;
    const int g   = blockIdx.y;               // ci group of 64
    const int tb  = blockIdx.z;

    const int ci_l = tid >> 2, pg = (tid & 3) * 16;
    const float* xp = X + ((size_t)tb * CIN + g * 64 + ci_l) * HWD + px0 + pg;
    #pragma unroll
    for (int q = 0; q < 4; ++q) {
        f32x4 v = *(const f32x4*)(xp + q * 4);
        #pragma unroll
        for (int e = 0; e < 4; ++e)
            t_[pg + q * 4 + e][ci_l] = f2bf(v[e]);
    }
    __syncthreads();
    const int px_l = tid >> 2, cg = (tid & 3) * 16;
    const int p  = px0 + px_l;
    const int pp = p + (p / WID) * 2 + 51;    // (h+1)*50 + (w+1)
    unsigned short* op = Xtp + (((size_t)tb * 4 + g) * PHW + pp) * 64 + cg;
    *(short8v*)op       = *(const short8v*)&t_[px_l][cg];
    *(short8v*)(op + 8) = *(const short8v*)&t_[px_l][cg + 8];
}

// ---- conv: r6/r12 proven cadence, 32x32x16 MFMA fragments; epilogue -> Y[tb][px][256co]
__global__ __launch_bounds__(256, 2) void conv15_k(
    const unsigned short* __restrict__ Xtp, const unsigned short* __restrict__ At,
    const float* __restrict__ Bs, unsigned short* __restrict__ Y, int tb_base)
{
    __shared__ short ldsA[2][8192];    // 128 rows x 128B, double-buffered (32 KB)
    __shared__ short ldsB[19200];      // slab: 300 padded px x 128B (37.5 KB)

    const int tid = threadIdx.x;
    const int wv  = tid >> 6, ln = tid & 63;
    const int l5  = ln >> 5;           // k-half selector
    const int wm  = wv >> 1,  wn = wv & 1;

    // bijective XCD swizzle, nwg=768 (q=96)
    const int orig = blockIdx.x;
    const int wg   = (orig & 7) * 96 + (orig >> 3);
    const int tb_l = wg / 24;
    const int rem  = wg - tb_l * 24;
    const int rt   = rem >> 1;           // row-tile 0..11 (4 image rows)
    const int by   = rem & 1;

    // B-fragment slab cell per 32-px N-tile (fixed per thread)
    int boff2[3];
    #pragma unroll
    for (int ni2 = 0; ni2 < 3; ++ni2) {
        const int p = wn * 96 + ni2 * 32 + (ln & 31);
        const int r = p / 48, c = p - r * 48;
        boff2[ni2] = (r + 1) * 50 + (c + 1);
    }
    // A rows for the two 32-co M-tiles
    const int rA0 = wm * 64 + (ln & 31);
    const int rA1 = rA0 + 32;

    const unsigned short* Asrc  = At + (size_t)by * 36 * 8192 + wv * 2048 + ln * 8;
    const unsigned short* slab0 = Xtp + (size_t)tb_l * 4 * PHW * 64 + (size_t)rt * 200 * 64;

    f32x16 acc2[2][3];
    #pragma unroll
    for (int i = 0; i < 2; ++i)
        #pragma unroll
        for (int j = 0; j < 3; ++j)
            #pragma unroll
            for (int e = 0; e < 16; ++e) acc2[i][j][e] = 0.f;

    for (int g = 0; g < 4; ++g) {
        // ---- stage B slab (once per ci-group): 2400 16B cells, pre-swizzled source
        const unsigned short* sg = slab0 + (size_t)g * PHW * 64;
        #pragma unroll
        for (int j = 0; j < 10; ++j) {
            const int cc = tid + 256 * j;
            if (cc < 2400) {
                const int p = cc >> 3, k = cc & 7;
                gload_lds16(sg + p * 64 + ((k ^ (p & 7)) << 3),
                            &ldsB[(wv * 64 + 256 * j) * 8]);
            }
        }
        // ---- stage A tile (g, tap0) into buf 0
        const unsigned short* ag = Asrc + (size_t)g * 9 * 8192;
        #pragma unroll
        for (int i = 0; i < 4; ++i)
            gload_lds16(ag + i * 512, &ldsA[0][wv * 2048 + i * 512]);
        asm volatile("s_waitcnt vmcnt(0)" ::: "memory");
        __builtin_amdgcn_sched_barrier(0);
        __builtin_amdgcn_s_barrier();

        #pragma unroll
        for (int tap = 0; tap < 9; ++tap) {
            const int cur = tap & 1;
            if (tap < 8) {                      // prefetch next A tile
                const unsigned short* an = ag + (size_t)(tap + 1) * 8192;
                #pragma unroll
                for (int i = 0; i < 4; ++i)
                    gload_lds16(an + i * 512, &ldsA[cur ^ 1][wv * 2048 + i * 512]);
            }
            const int toff = (tap / 3 - 1) * 50 + (tap % 3 - 1);
            #pragma unroll
            for (int ks4 = 0; ks4 < 4; ++ks4) {
                const int ak = ks4 * 2 + l5;    // k-chunk 0..7
                short8v a0, a1, b_[3];
                a0 = *(const short8v*)&ldsA[cur][rA0 * 64 + ((ak ^ (rA0 & 7)) << 3)];
                a1 = *(const short8v*)&ldsA[cur][rA1 * 64 + ((ak ^ (rA1 & 7)) << 3)];
                #pragma unroll
                for (int ni2 = 0; ni2 < 3; ++ni2) {
                    const int sp = boff2[ni2] + toff;
                    b_[ni2] = *(const short8v*)&ldsB[sp * 64 + ((ak ^ (sp & 7)) << 3)];
                }
                __builtin_amdgcn_s_setprio(1);
                #pragma unroll
                for (int ni2 = 0; ni2 < 3; ++ni2) {
                    acc2[0][ni2] = __builtin_amdgcn_mfma_f32_32x32x16_bf16(
                        a0, b_[ni2], acc2[0][ni2], 0, 0, 0);
                    acc2[1][ni2] = __builtin_amdgcn_mfma_f32_32x32x16_bf16(
                        a1, b_[ni2], acc2[1][ni2], 0, 0, 0);
                }
                __builtin_amdgcn_s_setprio(0);
            }
            asm volatile("s_waitcnt vmcnt(0)" ::: "memory");   // A(tap+1): 4 loads, L2-warm
            __builtin_amdgcn_sched_barrier(0);
            __builtin_amdgcn_s_barrier();
        }
    }

    // ---- epilogue: acc (+bias) -> bf16 -> swizzled LDS tiles -> Y[tb][px][co]
    // 32x32 C/D: col = ln&31 (px), row = (reg&3) + 8*(reg>>2) + 4*(ln>>5) (co)
    short* t0 = ldsB;                 // wn==0 tile: [96 px][128 co] shorts, swizzled
    short* t1 = &ldsA[0][0];          // wn==1 tile
    short* dst = wn ? t1 : t0;
    #pragma unroll
    for (int mi2 = 0; mi2 < 2; ++mi2) {
        #pragma unroll
        for (int ni2 = 0; ni2 < 3; ++ni2) {
            const int pl = ni2 * 32 + (ln & 31);            // 0..95
            #pragma unroll
            for (int rg = 0; rg < 4; ++rg) {
                const int co = wm * 64 + mi2 * 32 + rg * 8 + l5 * 4;  // 0..127
                const f32x4 b4 = *(const f32x4*)&Bs[by * 128 + co];
                const unsigned short h0 = f2bf(acc2[mi2][ni2][rg * 4 + 0] + b4[0]);
                const unsigned short h1 = f2bf(acc2[mi2][ni2][rg * 4 + 1] + b4[1]);
                const unsigned short h2 = f2bf(acc2[mi2][ni2][rg * 4 + 2] + b4[2]);
                const unsigned short h3 = f2bf(acc2[mi2][ni2][rg * 4 + 3] + b4[3]);
                uint2 u;
                u.x = (unsigned)h0 | ((unsigned)h1 << 16);
                u.y = (unsigned)h2 | ((unsigned)h3 << 16);
                *(uint2*)&dst[pl * 128 + (co ^ ((pl & 7) << 3))] = u;
            }
        }
    }
    __syncthreads();
    const int tbg = tb_base + tb_l;
    #pragma unroll
    for (int j = 0; j < 12; ++j) {
        const int pass = (j >= 6);
        const int tsk  = tid + 256 * (pass ? j - 6 : j);    // 0..1535
        const int pl   = tsk >> 4, oct = tsk & 15;
        const short* src = pass ? t1 : t0;
        short8v val = *(const short8v*)&src[pl * 128 + ((oct * 8) ^ ((pl & 7) << 3))];
        const int px = rt * 192 + pass * 96 + pl;
        *(short8v*)&Y[((size_t)tbg * HWD + px) * 256 + by * 128 + oct * 8] = val;
    }
}

// ---- fused LI scan + 1x1 heads. Y[tb][px][256co] bf16, out fp32.
__global__ __launch_bounds__(256) void liheads_k(
    const unsigned short* __restrict__ Y,
    const float* __restrict__ bw, const float* __restrict__ bb,
    const float* __restrict__ cw, const float* __restrict__ cb,
    float* __restrict__ out)
{
    __shared__ short Wl[32 * 256];          // [32 o][256 ci] swizzled (16 KB)
    __shared__ short Vl[32 * 256];          // [32 px][256 ci] swizzled (16 KB)

    const int tid = threadIdx.x;
    const int ln  = tid & 63;
    const int wv  = tid >> 6;
    const int mq  = wv & 1, nq = wv >> 1;
    const int px0 = blockIdx.x * 32;
    const int b   = blockIdx.y;

    // stage padded head-weight tile (rows: 0..11 box, 12..20 cls, 21..31 zero)
    {
        const int row = tid >> 3;
        const int cb8 = (tid & 7) * 32;
        #pragma unroll
        for (int j = 0; j < 4; ++j) {
            const int ci = cb8 + j * 8;
            short8v v8;
            if (row < 12) {
                #pragma unroll
                for (int e = 0; e < 8; ++e) v8[e] = (short)f2bf(bw[row * 256 + ci + e]);
            } else if (row < 21) {
                #pragma unroll
                for (int e = 0; e < 8; ++e) v8[e] = (short)f2bf(cw[(row - 12) * 256 + ci + e]);
            } else {
                #pragma unroll
                for (int e = 0; e < 8; ++e) v8[e] = 0;
            }
            *(short8v*)&Wl[row * 256 + (ci ^ ((row & 7) << 3))] = v8;
        }
    }
    __syncthreads();

    // preload A-frags (8 K-steps) for this wave's o-quad
    const int arow = mq * 16 + (ln & 15);
    const int kb   = (ln >> 4) * 8;
    short8v af[8];
    #pragma unroll
    for (int ks = 0; ks < 8; ++ks)
        af[ks] = *(const short8v*)&Wl[arow * 256 + ((ks * 32 + kb) ^ ((arow & 7) << 3))];

    float bias[4];
    #pragma unroll
    for (int r = 0; r < 4; ++r) {
        const int o = mq * 16 + (ln >> 4) * 4 + r;
        bias[r] = (o < 12) ? bb[o] : (o < 21 ? cb[o - 12] : 0.f);
    }

    const int px_l = tid >> 3, q8 = tid & 7;
    const unsigned short* xbase = Y + ((size_t)b * HWD + px0 + px_l) * 256 + q8 * 32;

    float v[32], cc[32];
    #pragma unroll
    for (int e = 0; e < 32; ++e) { v[e] = 0.f; cc[e] = 0.f; }

    uint4 xq[4];
    #pragma unroll
    for (int i = 0; i < 4; ++i) xq[i] = *(const uint4*)(xbase + i * 8);

    const int brow = nq * 16 + (ln & 15);
    const int px   = px0 + nq * 16 + (ln & 15);

    for (int t = 0; t < 16; ++t) {
        // LI update + pack v->bf16 into Vl
        #pragma unroll
        for (int i = 0; i < 4; ++i) {
            const unsigned uu0 = xq[i].x, uu1 = xq[i].y, uu2 = xq[i].z, uu3 = xq[i].w;
            const unsigned uus[4] = {uu0, uu1, uu2, uu3};
            unsigned outp[4];
            #pragma unroll
            for (int p = 0; p < 4; ++p) {
                const int e = i * 8 + p * 2;
                const float x0 = bf2f((unsigned short)(uus[p] & 0xffff));
                const float x1 = bf2f((unsigned short)(uus[p] >> 16));
                v[e]     += 0.1f * (cc[e]     - v[e]);
                v[e + 1] += 0.1f * (cc[e + 1] - v[e + 1]);
                cc[e]     = cc[e]     - 0.2f * cc[e]     + x0;
                cc[e + 1] = cc[e + 1] - 0.2f * cc[e + 1] + x1;
                outp[p] = (unsigned)f2bf(v[e]) | ((unsigned)f2bf(v[e + 1]) << 16);
            }
            uint4 w4; w4.x = outp[0]; w4.y = outp[1]; w4.z = outp[2]; w4.w = outp[3];
            *(uint4*)&Vl[px_l * 256 + ((q8 * 32 + i * 8) ^ ((px_l & 7) << 3))] = w4;
        }
        if (t < 15) {                         // prefetch next timestep (covers MFMA phase)
            const unsigned short* nb = xbase + (size_t)(t + 1) * SLICE;
            #pragma unroll
            for (int i = 0; i < 4; ++i) xq[i] = *(const uint4*)(nb + i * 8);
        }
        __syncthreads();

        f32x4 acc = {0.f, 0.f, 0.f, 0.f};
        #pragma unroll
        for (int ks = 0; ks < 8; ++ks) {
            short8v bf = *(const short8v*)&Vl[brow * 256 + ((ks * 32 + kb) ^ ((brow & 7) << 3))];
            acc = __builtin_amdgcn_mfma_f32_16x16x32_bf16(af[ks], bf, acc, 0, 0, 0);
        }
        #pragma unroll
        for (int r = 0; r < 4; ++r) {
            const int o = mq * 16 + (ln >> 4) * 4 + r;
            const float val = acc[r] + bias[r];
            if (o < 12)
                out[(((size_t)t * 4 + b) * 12 + o) * HWD + px] = val;
            else if (o < 21)
                out[(size_t)1769472 + (((size_t)t * 4 + b) * 9 + (o - 12)) * HWD + px] = val;
        }
        __syncthreads();                      // Vl consumed before next t's writes
    }
}

extern "C" void kernel_launch(void* const* d_in, const int* in_sizes, int n_in,
                              void* d_out, int out_size, void* d_ws, size_t ws_size,
                              hipStream_t stream)
{
    const float* X   = (const float*)d_in[0];  // (16,4,256,48,48)
    const float* cw3 = (const float*)d_in[1];  // (256,256,3,3)
    const float* cb3 = (const float*)d_in[2];  // (256,)
    const float* bw  = (const float*)d_in[3];
    const float* bb  = (const float*)d_in[4];
    const float* clw = (const float*)d_in[5];
    const float* clb = (const float*)d_in[6];
    float* out = (float*)d_out;

    unsigned short* Xtp = (unsigned short*)((char*)d_ws + WS_XT);
    unsigned short* At  = (unsigned short*)((char*)d_ws + WS_AT);
    unsigned short* Y   = (unsigned short*)((char*)d_ws + WS_Y);

    halo_zero_k<<<128, 256, 0, stream>>>(Xtp);  // halo zeros (both halves)
    prep_w_k<<<288, 256, 0, stream>>>(cw3, At);

    for (int half = 0; half < 2; ++half) {
        const float* Xh = X + (size_t)half * 32 * CIN * HWD;
        prep_x_k<<<dim3(36, 4, 32), 256, 0, stream>>>(Xh, Xtp);
        conv15_k<<<768, 256, 0, stream>>>(Xtp, At, cb3, Y, half * 32);
    }

    liheads_k<<<dim3(72, 4), 256, 0, stream>>>(Y, bw, bb, clw, clb, out);
}